// Round 10
// baseline (127.725 us; speedup 1.0000x reference)
//
#include <hip/hip_runtime.h>
#include <hip/hip_fp16.h>
#include <math.h>

#define NS_ 50000
#define NW_ 50000
#define IN_DIM_ 128
#define OUT_DIM_ 64

#define NSLAB 512          // partition slabs; slab_e = 3125 for E=1.6M
#define NB 782             // buckets = ceil(NW/64), bucket = dst >> 6
#define CAP 2272           // LDS edge capacity per bucket (mean 2046, +5 sigma; verified R9)

__device__ inline float leaky01(float x) { return x > 0.0f ? x : 0.01f * x; }

// z = h @ W_fc, fused t[row] = sum_c z[row][c] * w_attn[c].
// z stored SPLIT: z_lo[NS][32] dims 0-31, z_hi[NS][32] dims 32-63 (fp16),
// each 3.2 MB -> one half fits a 4 MB per-XCD L2 during aggregate's passes.
__global__ __launch_bounds__(256) void fc_kernel(const float* __restrict__ h,
                                                 const float* __restrict__ Wfc,
                                                 const float* __restrict__ w_attn,
                                                 __half* __restrict__ z_lo,
                                                 __half* __restrict__ z_hi,
                                                 float* __restrict__ t) {
    __shared__ float hs[64 * IN_DIM_];   // 32 KB
    int tid = threadIdx.x;
    int lane = tid & 63;
    int wv = tid >> 6;

    float Wc[IN_DIM_];
#pragma unroll
    for (int k = 0; k < IN_DIM_; ++k) Wc[k] = Wfc[k * OUT_DIM_ + lane];  // coalesced
    float wa = w_attn[lane];
    __half* zp = (lane < 32) ? z_lo : z_hi;
    int dim = lane & 31;

    int row0 = blockIdx.x * 64;
    int nrows = NS_ - row0; if (nrows > 64) nrows = 64;

    const float4* hg = (const float4*)(h + (size_t)row0 * IN_DIM_);
    float4* hs4 = (float4*)hs;
    int nv = nrows * (IN_DIM_ / 4);
    for (int i = tid; i < nv; i += 256) hs4[i] = hg[i];
    __syncthreads();

    int rend = wv * 16 + 16; if (rend > nrows) rend = nrows;
    for (int r = wv * 16; r < rend; r += 2) {
        bool two = (r + 1 < rend);
        const float4* h0 = (const float4*)(hs + r * IN_DIM_);
        const float4* h1 = (const float4*)(hs + (two ? r + 1 : r) * IN_DIM_);
        float a0 = 0, a1 = 0, a2 = 0, a3 = 0;
        float b0 = 0, b1 = 0, b2 = 0, b3 = 0;
#pragma unroll
        for (int k4 = 0; k4 < IN_DIM_ / 4; ++k4) {
            float4 u = h0[k4];   // wave-uniform LDS broadcast
            float4 v = h1[k4];
            a0 = fmaf(u.x, Wc[4 * k4 + 0], a0);
            a1 = fmaf(u.y, Wc[4 * k4 + 1], a1);
            a2 = fmaf(u.z, Wc[4 * k4 + 2], a2);
            a3 = fmaf(u.w, Wc[4 * k4 + 3], a3);
            b0 = fmaf(v.x, Wc[4 * k4 + 0], b0);
            b1 = fmaf(v.y, Wc[4 * k4 + 1], b1);
            b2 = fmaf(v.z, Wc[4 * k4 + 2], b2);
            b3 = fmaf(v.w, Wc[4 * k4 + 3], b3);
        }
        float za = (a0 + a1) + (a2 + a3);
        float zb = (b0 + b1) + (b2 + b3);
        zp[(size_t)(row0 + r) * 32 + dim] = __float2half(za);
        if (two) zp[(size_t)(row0 + r + 1) * 32 + dim] = __float2half(zb);
        float ta = za * wa, tb = zb * wa;
#pragma unroll
        for (int off = 32; off > 0; off >>= 1) {
            ta += __shfl_down(ta, off, 64);
            tb += __shfl_down(tb, off, 64);
        }
        if (lane == 0) {
            t[row0 + r] = ta;
            if (two) t[row0 + r + 1] = tb;
        }
    }
}

// One 1024-thread block per slab, SINGLE pass over edges: compute
// ex = exp(weight * leaky(t[src])) once, cache (ex, src|dlo|bucket) in
// statically-indexed registers across hist -> scan -> scatter.
// Metadata packed (cnt<<16)|off per (slab,bucket), stored [slab][bucket].
__global__ __launch_bounds__(1024) void partition_kernel(const float* __restrict__ weight,
                                                         const int* __restrict__ src,
                                                         const int* __restrict__ dst,
                                                         const float* __restrict__ t,
                                                         unsigned* __restrict__ meta_sb,
                                                         int2* __restrict__ edata,
                                                         int E, int slab_e) {
    __shared__ int hist[NB];
    __shared__ int part[1024];
    __shared__ int cur[NB];
    int tid = threadIdx.x;
    int s = blockIdx.x;
    int e0 = s * slab_e;
    int e1 = e0 + slab_e; if (e1 > E) e1 = E;
    int cnt = e1 - e0;

    for (int i = tid; i < NB; i += 1024) hist[i] = 0;
    __syncthreads();

    // pass over edges: compute + cache (static reg indices; slab_e <= 4096)
    float exr0 = 0, exr1 = 0, exr2 = 0, exr3 = 0;
    int mr0 = 0, mr1 = 0, mr2 = 0, mr3 = 0;
#define PART_LOAD(P, EXR, MR)                                              \
    {                                                                      \
        int i = tid + (P) * 1024;                                          \
        if (i < cnt) {                                                     \
            int e = e0 + i;                                                \
            int sr = src[e];                                               \
            int d = dst[e];                                                \
            float ev = weight[e] * leaky01(t[sr]);                         \
            EXR = __expf(ev);                                              \
            MR = sr | ((d & 63) << 16) | ((d >> 6) << 22);                 \
            atomicAdd(&hist[d >> 6], 1);                                   \
        }                                                                  \
    }
    PART_LOAD(0, exr0, mr0)
    PART_LOAD(1, exr1, mr1)
    PART_LOAD(2, exr2, mr2)
    PART_LOAD(3, exr3, mr3)
#undef PART_LOAD
    __syncthreads();

    // inclusive Hillis-Steele over 1024 (NB=782 padded with 0)
    int hv = (tid < NB) ? hist[tid] : 0;
    part[tid] = hv;
    __syncthreads();
#pragma unroll
    for (int off = 1; off < 1024; off <<= 1) {
        int v = (tid >= off) ? part[tid - off] : 0;
        __syncthreads();
        part[tid] += v;
        __syncthreads();
    }
    if (tid < NB) {
        int ex = part[tid] - hv;   // exclusive
        cur[tid] = ex;
        meta_sb[(size_t)s * NB + tid] = ((unsigned)hv << 16) | (unsigned)ex;  // coalesced
    }
    __syncthreads();

    // scatter from registers (no re-read)
#define PART_STORE(P, EXR, MR)                                             \
    {                                                                      \
        int i = tid + (P) * 1024;                                          \
        if (i < cnt) {                                                     \
            int b = ((unsigned)MR) >> 22;                                  \
            int pos = atomicAdd(&cur[b], 1);                               \
            edata[e0 + pos] = make_int2(__float_as_int(EXR), MR & 0x3FFFFF); \
        }                                                                  \
    }
    PART_STORE(0, exr0, mr0)
    PART_STORE(1, exr1, mr1)
    PART_STORE(2, exr2, mr2)
    PART_STORE(3, exr3, mr3)
#undef PART_STORE
}

// One 512-thread block per bucket (64 dsts):
//  pass1: gather bucket segments global->LDS sbuf; per-dst count + den
//  pass2: counting-sort int2 payloads into sorted[]
//  main:  8 waves x 8 dsts; TWO dim-passes (z_lo then z_hi), wave = 2 edges
//         x 32 dims per op -> each pass's gather footprint is 3.2 MB (L2-fit)
//  epilogue: per pass, matching half-wave stores 128B coalesced
__global__ __launch_bounds__(512) void aggregate_kernel(const unsigned* __restrict__ meta_sb,
                                                        const int2* __restrict__ edata,
                                                        const __half* __restrict__ z_lo,
                                                        const __half* __restrict__ z_hi,
                                                        float* __restrict__ out,
                                                        int slab_e) {
    __shared__ int2 sbuf[CAP];            // 18176 B
    __shared__ int2 sorted[CAP];          // 18176 B
    __shared__ unsigned short soff[NSLAB];// 1024 B
    __shared__ int arr[NSLAB + 1];        // 2052 B (segment boundaries)
    __shared__ float dden[64];            // 256 B
    __shared__ int dcnt[64];              // 256 B (counts, then cursor)
    __shared__ int dbase[65];             // 260 B

    int b = blockIdx.x;
    int tid = threadIdx.x;
    int lane = tid & 63;
    int wv = tid >> 6;

    {   // metadata: tid == slab id (512 threads == NSLAB); one packed read
        unsigned mv = meta_sb[(size_t)tid * NB + b];   // strided, L2/L3-served
        soff[tid] = (unsigned short)(mv & 0xFFFFu);
        arr[tid + 1] = (int)(mv >> 16);
    }
    if (tid == 0) arr[0] = 0;
    if (tid < 64) { dden[tid] = 0.0f; dcnt[tid] = 0; }
    __syncthreads();

    // inclusive Hillis-Steele on arr[1..512]
#pragma unroll
    for (int off = 1; off < NSLAB; off <<= 1) {
        int v = (tid >= off) ? arr[tid + 1 - off] : 0;
        __syncthreads();
        arr[tid + 1] += v;
        __syncthreads();
    }

    int total = arr[NSLAB];
    if (total > CAP) total = CAP;  // statistically impossible; avoid corruption

    // pass1: copy segments + per-dst count/den. 128 groups x 4 lanes.
    int gid = tid >> 2, l4 = tid & 3;
    for (int s = gid; s < NSLAB; s += 128) {
        int base = arr[s];
        int len = arr[s + 1] - base;
        int so = (int)soff[s];
        for (int j = l4; j < len; j += 4) {
            int p = base + j;
            if (p < CAP) {
                int2 e = edata[(size_t)s * slab_e + so + j];
                sbuf[p] = e;
                int d6 = (e.y >> 16) & 63;
                atomicAdd(&dcnt[d6], 1);
                atomicAdd(&dden[d6], __int_as_float(e.x));
            }
        }
    }
    __syncthreads();

    // per-dst exclusive scan (single wave); dcnt becomes the scatter cursor
    if (tid < 64) {
        int v = dcnt[tid];
        int incl = v;
#pragma unroll
        for (int off = 1; off < 64; off <<= 1) {
            int u = __shfl_up(incl, off, 64);
            if (tid >= off) incl += u;
        }
        dbase[tid + 1] = incl;
        dcnt[tid] = incl - v;   // exclusive start = cursor
        if (tid == 0) dbase[0] = 0;
    }
    __syncthreads();

    // pass2: counting-sort payloads into sorted[]
    for (int k = tid; k < total; k += 512) {
        int2 e = sbuf[k];
        int d6 = (e.y >> 16) & 63;
        int pos = atomicAdd(&dcnt[d6], 1);
        sorted[pos] = e;
    }
    __syncthreads();

    // main: 8 waves x 8 dsts; 2 edges x 32 dims per wave-op; two z passes
    int half = lane >> 5;   // edge slot
    int dim = lane & 31;    // output dim within half
    for (int q = 0; q < 8; ++q) {
        int d6 = wv * 8 + q;
        int d = b * 64 + d6;
        if (d >= NW_) continue;
        int a0 = dbase[d6];
        int n = dbase[d6 + 1] - a0;
        float invdn = (n > 0) ? 1.0f / dden[d6] : 0.0f;
#pragma unroll
        for (int pass = 0; pass < 2; ++pass) {
            const __half* zp = pass ? z_hi : z_lo;
            float c0 = 0, c1 = 0, c2 = 0, c3 = 0, c4 = 0, c5 = 0, c6 = 0, c7 = 0;
            int j = 0;
            for (; j + 16 <= n; j += 16) {
                int bse = a0 + j + half;
                int2 e0 = sorted[bse + 0],  e1 = sorted[bse + 2];
                int2 e2 = sorted[bse + 4],  e3 = sorted[bse + 6];
                int2 e4 = sorted[bse + 8],  e5 = sorted[bse + 10];
                int2 e6 = sorted[bse + 12], e7 = sorted[bse + 14];
                c0 = fmaf(__int_as_float(e0.x), __half2float(zp[(e0.y & 0xFFFF) * 32 + dim]), c0);
                c1 = fmaf(__int_as_float(e1.x), __half2float(zp[(e1.y & 0xFFFF) * 32 + dim]), c1);
                c2 = fmaf(__int_as_float(e2.x), __half2float(zp[(e2.y & 0xFFFF) * 32 + dim]), c2);
                c3 = fmaf(__int_as_float(e3.x), __half2float(zp[(e3.y & 0xFFFF) * 32 + dim]), c3);
                c4 = fmaf(__int_as_float(e4.x), __half2float(zp[(e4.y & 0xFFFF) * 32 + dim]), c4);
                c5 = fmaf(__int_as_float(e5.x), __half2float(zp[(e5.y & 0xFFFF) * 32 + dim]), c5);
                c6 = fmaf(__int_as_float(e6.x), __half2float(zp[(e6.y & 0xFFFF) * 32 + dim]), c6);
                c7 = fmaf(__int_as_float(e7.x), __half2float(zp[(e7.y & 0xFFFF) * 32 + dim]), c7);
            }
            for (; j < n; j += 2) {
                int idx = j + half;
                if (idx < n) {
                    int2 e = sorted[a0 + idx];
                    c0 = fmaf(__int_as_float(e.x), __half2float(zp[(e.y & 0xFFFF) * 32 + dim]), c0);
                }
            }
            float acc = ((c0 + c1) + (c2 + c3)) + ((c4 + c5) + (c6 + c7));
            acc += __shfl_xor(acc, 32, 64);   // combine the two edge-slots
            if (half == pass)                 // 32 lanes store 128B coalesced
                out[(size_t)d * OUT_DIM_ + pass * 32 + dim] = acc * invdn;
        }
    }
}

extern "C" void kernel_launch(void* const* d_in, const int* in_sizes, int n_in,
                              void* d_out, int out_size, void* d_ws, size_t ws_size,
                              hipStream_t stream) {
    const float* h      = (const float*)d_in[0];
    const float* Wfc    = (const float*)d_in[1];
    const float* w_attn = (const float*)d_in[2];
    const float* weight = (const float*)d_in[3];
    const int*   src    = (const int*)d_in[4];
    const int*   dst    = (const int*)d_in[5];
    int E = in_sizes[3];
    float* out = (float*)d_out;

    int slab_e = (E + NSLAB - 1) / NSLAB;  // 3125 for E=1.6M (must be <= 4096)

    // workspace: edata (8B-aligned) | z_lo | z_hi | t | meta
    int2*     edata = (int2*)d_ws;                                  // E
    __half*   z_lo  = (__half*)(edata + (size_t)E);                 // NS*32
    __half*   z_hi  = z_lo + (size_t)NS_ * 32;                      // NS*32
    float*    t     = (float*)(z_hi + (size_t)NS_ * 32);            // NS
    unsigned* meta  = (unsigned*)(t + NS_);                         // NSLAB*NB

    fc_kernel<<<(NS_ + 63) / 64, 256, 0, stream>>>(h, Wfc, w_attn, z_lo, z_hi, t);

    partition_kernel<<<NSLAB, 1024, 0, stream>>>(weight, src, dst, t, meta, edata, E, slab_e);

    aggregate_kernel<<<NB, 512, 0, stream>>>(meta, edata, z_lo, z_hi, out, slab_e);
}

// Round 11
// 112.023 us; speedup vs baseline: 1.1402x; 1.1402x over previous
//
#include <hip/hip_runtime.h>
#include <hip/hip_fp16.h>
#include <math.h>

#define NS_ 50000
#define NW_ 50000
#define IN_DIM_ 128
#define OUT_DIM_ 64

#define NSLAB 512          // partition slabs; slab_e = 3125 for E=1.6M
#define NB 1563            // buckets = ceil(NW/32), bucket = dst >> 5
#define CAP 1280           // LDS edge capacity per bucket (mean 1024, +8 sigma)

__device__ inline float leaky01(float x) { return x > 0.0f ? x : 0.01f * x; }

// z = h @ W_fc (fp16 out), fused t[row] = sum_c z[row][c] * w_attn[c]
__global__ __launch_bounds__(256) void fc_kernel(const float* __restrict__ h,
                                                 const float* __restrict__ Wfc,
                                                 const float* __restrict__ w_attn,
                                                 __half* __restrict__ z16,
                                                 float* __restrict__ t) {
    __shared__ float hs[64 * IN_DIM_];   // 32 KB
    int tid = threadIdx.x;
    int lane = tid & 63;
    int wv = tid >> 6;

    float Wc[IN_DIM_];
#pragma unroll
    for (int k = 0; k < IN_DIM_; ++k) Wc[k] = Wfc[k * OUT_DIM_ + lane];  // coalesced
    float wa = w_attn[lane];

    int row0 = blockIdx.x * 64;
    int nrows = NS_ - row0; if (nrows > 64) nrows = 64;

    const float4* hg = (const float4*)(h + (size_t)row0 * IN_DIM_);
    float4* hs4 = (float4*)hs;
    int nv = nrows * (IN_DIM_ / 4);
    for (int i = tid; i < nv; i += 256) hs4[i] = hg[i];
    __syncthreads();

    int rend = wv * 16 + 16; if (rend > nrows) rend = nrows;
    for (int r = wv * 16; r < rend; r += 2) {
        bool two = (r + 1 < rend);
        const float4* h0 = (const float4*)(hs + r * IN_DIM_);
        const float4* h1 = (const float4*)(hs + (two ? r + 1 : r) * IN_DIM_);
        float a0 = 0, a1 = 0, a2 = 0, a3 = 0;
        float b0 = 0, b1 = 0, b2 = 0, b3 = 0;
#pragma unroll
        for (int k4 = 0; k4 < IN_DIM_ / 4; ++k4) {
            float4 u = h0[k4];   // wave-uniform LDS broadcast
            float4 v = h1[k4];
            a0 = fmaf(u.x, Wc[4 * k4 + 0], a0);
            a1 = fmaf(u.y, Wc[4 * k4 + 1], a1);
            a2 = fmaf(u.z, Wc[4 * k4 + 2], a2);
            a3 = fmaf(u.w, Wc[4 * k4 + 3], a3);
            b0 = fmaf(v.x, Wc[4 * k4 + 0], b0);
            b1 = fmaf(v.y, Wc[4 * k4 + 1], b1);
            b2 = fmaf(v.z, Wc[4 * k4 + 2], b2);
            b3 = fmaf(v.w, Wc[4 * k4 + 3], b3);
        }
        float za = (a0 + a1) + (a2 + a3);
        float zb = (b0 + b1) + (b2 + b3);
        z16[(size_t)(row0 + r) * OUT_DIM_ + lane] = __float2half(za);
        if (two) z16[(size_t)(row0 + r + 1) * OUT_DIM_ + lane] = __float2half(zb);
        float ta = za * wa, tb = zb * wa;
#pragma unroll
        for (int off = 32; off > 0; off >>= 1) {
            ta += __shfl_down(ta, off, 64);
            tb += __shfl_down(tb, off, 64);
        }
        if (lane == 0) {
            t[row0 + r] = ta;
            if (two) t[row0 + r + 1] = tb;
        }
    }
}

// One 1024-thread block per slab, single pass over edges: compute
// ex = exp(weight * leaky(t[src])) once, cache (ex, sr|dlo|bucket) in
// statically-indexed registers across hist -> scan -> scatter.
// bucket = dst>>5 (11 bits), dlo = dst&31 (5 bits), sr (16 bits).
// Metadata packed (cnt<<16)|off per (slab,bucket), stored [slab][bucket].
__global__ __launch_bounds__(1024) void partition_kernel(const float* __restrict__ weight,
                                                         const int* __restrict__ src,
                                                         const int* __restrict__ dst,
                                                         const float* __restrict__ t,
                                                         unsigned* __restrict__ meta_sb,
                                                         int2* __restrict__ edata,
                                                         int E, int slab_e) {
    __shared__ int hist[NB];
    __shared__ int part[1024];
    __shared__ int cur[NB];
    int tid = threadIdx.x;
    int s = blockIdx.x;
    int e0 = s * slab_e;
    int e1 = e0 + slab_e; if (e1 > E) e1 = E;
    int cnt = e1 - e0;

    for (int i = tid; i < NB; i += 1024) hist[i] = 0;
    __syncthreads();

    // pass over edges: compute + cache (static reg indices; slab_e <= 4096)
    float exr0 = 0, exr1 = 0, exr2 = 0, exr3 = 0;
    int mr0 = 0, mr1 = 0, mr2 = 0, mr3 = 0;
#define PART_LOAD(P, EXR, MR)                                              \
    {                                                                      \
        int i = tid + (P) * 1024;                                          \
        if (i < cnt) {                                                     \
            int e = e0 + i;                                                \
            int sr = src[e];                                               \
            int d = dst[e];                                                \
            float ev = weight[e] * leaky01(t[sr]);                         \
            EXR = __expf(ev);                                              \
            MR = sr | ((d & 31) << 16) | ((d >> 5) << 21);                 \
            atomicAdd(&hist[d >> 5], 1);                                   \
        }                                                                  \
    }
    PART_LOAD(0, exr0, mr0)
    PART_LOAD(1, exr1, mr1)
    PART_LOAD(2, exr2, mr2)
    PART_LOAD(3, exr3, mr3)
#undef PART_LOAD
    __syncthreads();

    // scan over NB=1563: 2 elements per thread, Hillis-Steele on pair sums
    int i0 = 2 * tid, i1 = 2 * tid + 1;
    int h0 = (i0 < NB) ? hist[i0] : 0;
    int h1 = (i1 < NB) ? hist[i1] : 0;
    int pairv = h0 + h1;
    part[tid] = pairv;
    __syncthreads();
#pragma unroll
    for (int off = 1; off < 1024; off <<= 1) {
        int v = (tid >= off) ? part[tid - off] : 0;
        __syncthreads();
        part[tid] += v;
        __syncthreads();
    }
    int base = part[tid] - pairv;   // exclusive start of pair
    if (i0 < NB) {
        cur[i0] = base;
        meta_sb[(size_t)s * NB + i0] = ((unsigned)h0 << 16) | (unsigned)base;
    }
    if (i1 < NB) {
        int b1 = base + h0;
        cur[i1] = b1;
        meta_sb[(size_t)s * NB + i1] = ((unsigned)h1 << 16) | (unsigned)b1;
    }
    __syncthreads();

    // scatter from registers (no re-read)
#define PART_STORE(P, EXR, MR)                                             \
    {                                                                      \
        int i = tid + (P) * 1024;                                          \
        if (i < cnt) {                                                     \
            int b = ((unsigned)MR) >> 21;                                  \
            int pos = atomicAdd(&cur[b], 1);                               \
            edata[e0 + pos] = make_int2(__float_as_int(EXR), MR & 0x1FFFFF); \
        }                                                                  \
    }
    PART_STORE(0, exr0, mr0)
    PART_STORE(1, exr1, mr1)
    PART_STORE(2, exr2, mr2)
    PART_STORE(3, exr3, mr3)
#undef PART_STORE
}

// One 512-thread block per bucket (32 dsts), ~24 KB LDS -> 32-wave occupancy:
//  pass1: gather bucket segments global->LDS sbuf; per-dst count + den
//         (no max-subtraction: |e| <= ~1.5 so exp(e) is safe and exact)
//  pass2: counting-sort int2 payloads into sorted[]
//  main:  8 waves x 4 dsts, 8 independent gather-FMA chains from sorted[]
//  epilogue: out = acc / den
__global__ __launch_bounds__(512) void aggregate_kernel(const unsigned* __restrict__ meta_sb,
                                                        const int2* __restrict__ edata,
                                                        const __half* __restrict__ z16,
                                                        float* __restrict__ out,
                                                        int slab_e) {
    __shared__ int2 sbuf[CAP];            // 10240 B
    __shared__ int2 sorted[CAP];          // 10240 B
    __shared__ unsigned short soff[NSLAB];// 1024 B
    __shared__ int arr[NSLAB + 1];        // 2052 B (segment boundaries)
    __shared__ float dden[32];
    __shared__ int dcnt[32];              // counts, then cursor
    __shared__ int dbase[33];
    // total ~24 KB

    int b = blockIdx.x;
    int tid = threadIdx.x;
    int lane = tid & 63;
    int wv = tid >> 6;

    {   // metadata: tid == slab id (512 threads == NSLAB); one packed read
        unsigned mv = meta_sb[(size_t)tid * NB + b];   // strided, L2/L3-served
        soff[tid] = (unsigned short)(mv & 0xFFFFu);
        arr[tid + 1] = (int)(mv >> 16);
    }
    if (tid < 32) { dden[tid] = 0.0f; dcnt[tid] = 0; }
    if (tid == 0) arr[0] = 0;
    __syncthreads();

    // inclusive Hillis-Steele on arr[1..512]
#pragma unroll
    for (int off = 1; off < NSLAB; off <<= 1) {
        int v = (tid >= off) ? arr[tid + 1 - off] : 0;
        __syncthreads();
        arr[tid + 1] += v;
        __syncthreads();
    }

    int total = arr[NSLAB];
    if (total > CAP) total = CAP;  // statistically impossible; avoid corruption

    // pass1: copy segments + per-dst count/den. 256 groups x 2 lanes.
    int gid = tid >> 1, l2 = tid & 1;
    for (int s = gid; s < NSLAB; s += 256) {
        int base = arr[s];
        int len = arr[s + 1] - base;
        int so = (int)soff[s];
        for (int j = l2; j < len; j += 2) {
            int p = base + j;
            if (p < CAP) {
                int2 e = edata[(size_t)s * slab_e + so + j];
                sbuf[p] = e;
                int d5 = (e.y >> 16) & 31;
                atomicAdd(&dcnt[d5], 1);
                atomicAdd(&dden[d5], __int_as_float(e.x));
            }
        }
    }
    __syncthreads();

    // per-dst exclusive scan (first 32 lanes); dcnt becomes the scatter cursor
    if (tid < 32) {
        int v = dcnt[tid];
        int incl = v;
#pragma unroll
        for (int off = 1; off < 32; off <<= 1) {
            int u = __shfl_up(incl, off, 64);
            if (tid >= off) incl += u;
        }
        dbase[tid + 1] = incl;
        dcnt[tid] = incl - v;   // exclusive start = cursor
        if (tid == 0) dbase[0] = 0;
    }
    __syncthreads();

    // pass2: counting-sort payloads into sorted[]
    for (int k = tid; k < total; k += 512) {
        int2 e = sbuf[k];
        int d5 = (e.y >> 16) & 31;
        int pos = atomicAdd(&dcnt[d5], 1);
        sorted[pos] = e;
    }
    __syncthreads();

    // main: 8 waves x 4 dsts, 8 independent gather-FMA chains
    for (int q = 0; q < 4; ++q) {
        int d5 = wv * 4 + q;
        int d = b * 32 + d5;
        if (d >= NW_) continue;
        int a0 = dbase[d5];
        int n = dbase[d5 + 1] - a0;
        float r = 0.0f;
        if (n > 0) {
            float a0f = 0.f, a1f = 0.f, a2f = 0.f, a3f = 0.f;
            float a4f = 0.f, a5f = 0.f, a6f = 0.f, a7f = 0.f;
            int j = 0;
            for (; j + 8 <= n; j += 8) {
                int2 e0 = sorted[a0 + j + 0], e1 = sorted[a0 + j + 1];
                int2 e2 = sorted[a0 + j + 2], e3 = sorted[a0 + j + 3];
                int2 e4 = sorted[a0 + j + 4], e5 = sorted[a0 + j + 5];
                int2 e6 = sorted[a0 + j + 6], e7 = sorted[a0 + j + 7];
                a0f = fmaf(__int_as_float(e0.x), __half2float(z16[(e0.y & 0xFFFF) * OUT_DIM_ + lane]), a0f);
                a1f = fmaf(__int_as_float(e1.x), __half2float(z16[(e1.y & 0xFFFF) * OUT_DIM_ + lane]), a1f);
                a2f = fmaf(__int_as_float(e2.x), __half2float(z16[(e2.y & 0xFFFF) * OUT_DIM_ + lane]), a2f);
                a3f = fmaf(__int_as_float(e3.x), __half2float(z16[(e3.y & 0xFFFF) * OUT_DIM_ + lane]), a3f);
                a4f = fmaf(__int_as_float(e4.x), __half2float(z16[(e4.y & 0xFFFF) * OUT_DIM_ + lane]), a4f);
                a5f = fmaf(__int_as_float(e5.x), __half2float(z16[(e5.y & 0xFFFF) * OUT_DIM_ + lane]), a5f);
                a6f = fmaf(__int_as_float(e6.x), __half2float(z16[(e6.y & 0xFFFF) * OUT_DIM_ + lane]), a6f);
                a7f = fmaf(__int_as_float(e7.x), __half2float(z16[(e7.y & 0xFFFF) * OUT_DIM_ + lane]), a7f);
            }
            for (; j < n; ++j) {
                int2 e = sorted[a0 + j];
                a0f = fmaf(__int_as_float(e.x), __half2float(z16[(e.y & 0xFFFF) * OUT_DIM_ + lane]), a0f);
            }
            float dn = dden[d5];
            r = (((a0f + a1f) + (a2f + a3f)) + ((a4f + a5f) + (a6f + a7f))) / dn;
        }
        out[(size_t)d * OUT_DIM_ + lane] = r;
    }
}

extern "C" void kernel_launch(void* const* d_in, const int* in_sizes, int n_in,
                              void* d_out, int out_size, void* d_ws, size_t ws_size,
                              hipStream_t stream) {
    const float* h      = (const float*)d_in[0];
    const float* Wfc    = (const float*)d_in[1];
    const float* w_attn = (const float*)d_in[2];
    const float* weight = (const float*)d_in[3];
    const int*   src    = (const int*)d_in[4];
    const int*   dst    = (const int*)d_in[5];
    int E = in_sizes[3];
    float* out = (float*)d_out;

    int slab_e = (E + NSLAB - 1) / NSLAB;  // 3125 for E=1.6M (must be <= 4096)

    // workspace: edata (8B-aligned) | z16 | t | meta
    int2*     edata = (int2*)d_ws;                                  // E
    __half*   z16   = (__half*)(edata + (size_t)E);                 // NS*64
    float*    t     = (float*)(z16 + (size_t)NS_ * OUT_DIM_);       // NS
    unsigned* meta  = (unsigned*)(t + NS_);                         // NSLAB*NB

    fc_kernel<<<(NS_ + 63) / 64, 256, 0, stream>>>(h, Wfc, w_attn, z16, t);

    partition_kernel<<<NSLAB, 1024, 0, stream>>>(weight, src, dst, t, meta, edata, E, slab_e);

    aggregate_kernel<<<NB, 512, 0, stream>>>(meta, edata, z16, out, slab_e);
}

// Round 12
// 107.218 us; speedup vs baseline: 1.1913x; 1.0448x over previous
//
#include <hip/hip_runtime.h>
#include <hip/hip_fp16.h>
#include <math.h>

#define NS_ 50000
#define NW_ 50000
#define IN_DIM_ 128
#define OUT_DIM_ 64

#define NSLAB 512          // partition slabs; slab_e = 3125 for E=1.6M
#define NB 1563            // buckets = ceil(NW/32), bucket = dst >> 5
#define CAP 1280           // LDS edge capacity per bucket (mean 1024, +8 sigma; verified R11)

__device__ inline float leaky01(float x) { return x > 0.0f ? x : 0.01f * x; }

// z = h @ W_fc (fp16 out), fused t[row] = sum_c z[row][c] * w_attn[c]
__global__ __launch_bounds__(256) void fc_kernel(const float* __restrict__ h,
                                                 const float* __restrict__ Wfc,
                                                 const float* __restrict__ w_attn,
                                                 __half* __restrict__ z16,
                                                 float* __restrict__ t) {
    __shared__ float hs[64 * IN_DIM_];   // 32 KB
    int tid = threadIdx.x;
    int lane = tid & 63;
    int wv = tid >> 6;

    float Wc[IN_DIM_];
#pragma unroll
    for (int k = 0; k < IN_DIM_; ++k) Wc[k] = Wfc[k * OUT_DIM_ + lane];  // coalesced
    float wa = w_attn[lane];

    int row0 = blockIdx.x * 64;
    int nrows = NS_ - row0; if (nrows > 64) nrows = 64;

    const float4* hg = (const float4*)(h + (size_t)row0 * IN_DIM_);
    float4* hs4 = (float4*)hs;
    int nv = nrows * (IN_DIM_ / 4);
    for (int i = tid; i < nv; i += 256) hs4[i] = hg[i];
    __syncthreads();

    int rend = wv * 16 + 16; if (rend > nrows) rend = nrows;
    for (int r = wv * 16; r < rend; r += 2) {
        bool two = (r + 1 < rend);
        const float4* h0 = (const float4*)(hs + r * IN_DIM_);
        const float4* h1 = (const float4*)(hs + (two ? r + 1 : r) * IN_DIM_);
        float a0 = 0, a1 = 0, a2 = 0, a3 = 0;
        float b0 = 0, b1 = 0, b2 = 0, b3 = 0;
#pragma unroll
        for (int k4 = 0; k4 < IN_DIM_ / 4; ++k4) {
            float4 u = h0[k4];   // wave-uniform LDS broadcast
            float4 v = h1[k4];
            a0 = fmaf(u.x, Wc[4 * k4 + 0], a0);
            a1 = fmaf(u.y, Wc[4 * k4 + 1], a1);
            a2 = fmaf(u.z, Wc[4 * k4 + 2], a2);
            a3 = fmaf(u.w, Wc[4 * k4 + 3], a3);
            b0 = fmaf(v.x, Wc[4 * k4 + 0], b0);
            b1 = fmaf(v.y, Wc[4 * k4 + 1], b1);
            b2 = fmaf(v.z, Wc[4 * k4 + 2], b2);
            b3 = fmaf(v.w, Wc[4 * k4 + 3], b3);
        }
        float za = (a0 + a1) + (a2 + a3);
        float zb = (b0 + b1) + (b2 + b3);
        z16[(size_t)(row0 + r) * OUT_DIM_ + lane] = __float2half(za);
        if (two) z16[(size_t)(row0 + r + 1) * OUT_DIM_ + lane] = __float2half(zb);
        float ta = za * wa, tb = zb * wa;
#pragma unroll
        for (int off = 32; off > 0; off >>= 1) {
            ta += __shfl_down(ta, off, 64);
            tb += __shfl_down(tb, off, 64);
        }
        if (lane == 0) {
            t[row0 + r] = ta;
            if (two) t[row0 + r + 1] = tb;
        }
    }
}

// One 1024-thread block per slab, single pass over edges; two-level wave scan
// (no Hillis-Steele barrier storm). Metadata packed (cnt<<16)|off, [slab][bucket].
__global__ __launch_bounds__(1024) void partition_kernel(const float* __restrict__ weight,
                                                         const int* __restrict__ src,
                                                         const int* __restrict__ dst,
                                                         const float* __restrict__ t,
                                                         unsigned* __restrict__ meta_sb,
                                                         int2* __restrict__ edata,
                                                         int E, int slab_e) {
    __shared__ int hist[NB];
    __shared__ int cur[NB];
    __shared__ int wsum[16];
    int tid = threadIdx.x;
    int lane = tid & 63;
    int wv = tid >> 6;
    int s = blockIdx.x;
    int e0 = s * slab_e;
    int e1 = e0 + slab_e; if (e1 > E) e1 = E;
    int cnt = e1 - e0;

    for (int i = tid; i < NB; i += 1024) hist[i] = 0;
    __syncthreads();

    // pass over edges: compute + cache (static reg indices; slab_e <= 4096)
    float exr0 = 0, exr1 = 0, exr2 = 0, exr3 = 0;
    int mr0 = 0, mr1 = 0, mr2 = 0, mr3 = 0;
#define PART_LOAD(P, EXR, MR)                                              \
    {                                                                      \
        int i = tid + (P) * 1024;                                          \
        if (i < cnt) {                                                     \
            int e = e0 + i;                                                \
            int sr = src[e];                                               \
            int d = dst[e];                                                \
            float ev = weight[e] * leaky01(t[sr]);                         \
            EXR = __expf(ev);                                              \
            MR = sr | ((d & 31) << 16) | ((d >> 5) << 21);                 \
            atomicAdd(&hist[d >> 5], 1);                                   \
        }                                                                  \
    }
    PART_LOAD(0, exr0, mr0)
    PART_LOAD(1, exr1, mr1)
    PART_LOAD(2, exr2, mr2)
    PART_LOAD(3, exr3, mr3)
#undef PART_LOAD
    __syncthreads();

    // scan over NB=1563: 2 buckets/thread; wave shfl-scan + cross-wave offsets
    int i0 = 2 * tid, i1 = 2 * tid + 1;
    int h0 = (i0 < NB) ? hist[i0] : 0;
    int h1 = (i1 < NB) ? hist[i1] : 0;
    int pairv = h0 + h1;
    int incl = pairv;
#pragma unroll
    for (int off = 1; off < 64; off <<= 1) {
        int u = __shfl_up(incl, off, 64);
        if (lane >= off) incl += u;
    }
    if (lane == 63) wsum[wv] = incl;
    __syncthreads();
    int woff = 0;
    for (int w = 0; w < wv; ++w) woff += wsum[w];
    incl += woff;
    int base = incl - pairv;   // exclusive start of this thread's pair
    if (i0 < NB) {
        cur[i0] = base;
        meta_sb[(size_t)s * NB + i0] = ((unsigned)h0 << 16) | (unsigned)base;
    }
    if (i1 < NB) {
        int b1 = base + h0;
        cur[i1] = b1;
        meta_sb[(size_t)s * NB + i1] = ((unsigned)h1 << 16) | (unsigned)b1;
    }
    __syncthreads();

    // scatter from registers (no re-read)
#define PART_STORE(P, EXR, MR)                                             \
    {                                                                      \
        int i = tid + (P) * 1024;                                          \
        if (i < cnt) {                                                     \
            int b = ((unsigned)MR) >> 21;                                  \
            int pos = atomicAdd(&cur[b], 1);                               \
            edata[e0 + pos] = make_int2(__float_as_int(EXR), MR & 0x1FFFFF); \
        }                                                                  \
    }
    PART_STORE(0, exr0, mr0)
    PART_STORE(1, exr1, mr1)
    PART_STORE(2, exr2, mr2)
    PART_STORE(3, exr3, mr3)
#undef PART_STORE
}

// One 512-thread block per bucket (32 dsts):
//  pass1: gather bucket segments global->LDS sbuf; per-dst count + den
//  pass2: counting-sort int2 payloads into sorted[]
//  main:  8 waves x 4 dsts; WIDE gather: lane = (edge-slot qg = lane>>4,
//         dim-slice dl = lane&15); each lane loads uint2 (4 dims of one row)
//         -> 512 B per wave-op = 4 edge rows; 32 edges in flight per wave.
//  epilogue: 2x shfl_xor combine, lanes 0-15 store float4 (256 B/dst).
__global__ __launch_bounds__(512) void aggregate_kernel(const unsigned* __restrict__ meta_sb,
                                                        const int2* __restrict__ edata,
                                                        const __half* __restrict__ z16,
                                                        float* __restrict__ out,
                                                        int slab_e) {
    __shared__ int2 sbuf[CAP];            // 10240 B
    __shared__ int2 sorted[CAP];          // 10240 B
    __shared__ unsigned short soff[NSLAB];// 1024 B
    __shared__ int arr[NSLAB + 1];        // 2052 B (segment boundaries)
    __shared__ int wsum[8];
    __shared__ float dden[32];
    __shared__ int dcnt[32];              // counts, then cursor
    __shared__ int dbase[33];

    int b = blockIdx.x;
    int tid = threadIdx.x;
    int lane = tid & 63;
    int wv = tid >> 6;

    int cntv;
    {   // metadata: tid == slab id (512 threads == NSLAB); one packed read
        unsigned mv = meta_sb[(size_t)tid * NB + b];   // strided, L2/L3-served
        soff[tid] = (unsigned short)(mv & 0xFFFFu);
        cntv = (int)(mv >> 16);
    }
    if (tid < 32) { dden[tid] = 0.0f; dcnt[tid] = 0; }

    // two-level inclusive scan of cntv -> arr[tid+1]
    int incl = cntv;
#pragma unroll
    for (int off = 1; off < 64; off <<= 1) {
        int u = __shfl_up(incl, off, 64);
        if (lane >= off) incl += u;
    }
    if (lane == 63) wsum[wv] = incl;
    __syncthreads();
    int woff = 0;
    for (int w = 0; w < wv; ++w) woff += wsum[w];
    incl += woff;
    arr[tid + 1] = incl;
    if (tid == 0) arr[0] = 0;
    __syncthreads();

    int total = arr[NSLAB];
    if (total > CAP) total = CAP;  // statistically impossible; avoid corruption

    // pass1: copy segments + per-dst count/den. 256 groups x 2 lanes.
    int gid = tid >> 1, l2 = tid & 1;
    for (int s = gid; s < NSLAB; s += 256) {
        int base = arr[s];
        int len = arr[s + 1] - base;
        int so = (int)soff[s];
        for (int j = l2; j < len; j += 2) {
            int p = base + j;
            if (p < CAP) {
                int2 e = edata[(size_t)s * slab_e + so + j];
                sbuf[p] = e;
                int d5 = (e.y >> 16) & 31;
                atomicAdd(&dcnt[d5], 1);
                atomicAdd(&dden[d5], __int_as_float(e.x));
            }
        }
    }
    __syncthreads();

    // per-dst exclusive scan (first 32 lanes); dcnt becomes the scatter cursor
    if (tid < 32) {
        int v = dcnt[tid];
        int iv = v;
#pragma unroll
        for (int off = 1; off < 32; off <<= 1) {
            int u = __shfl_up(iv, off, 64);
            if (tid >= off) iv += u;
        }
        dbase[tid + 1] = iv;
        dcnt[tid] = iv - v;   // exclusive start = cursor
        if (tid == 0) dbase[0] = 0;
    }
    __syncthreads();

    // pass2: counting-sort payloads into sorted[]
    for (int k = tid; k < total; k += 512) {
        int2 e = sbuf[k];
        int d5 = (e.y >> 16) & 31;
        int pos = atomicAdd(&dcnt[d5], 1);
        sorted[pos] = e;
    }
    __syncthreads();

    // main: 8 waves x 4 dsts; wide-gather loop
    int qg = lane >> 4;    // edge slot 0..3
    int dl = lane & 15;    // dim slice: dims dl*4 .. dl*4+3
    const unsigned short* z16u = (const unsigned short*)z16;
    for (int q = 0; q < 4; ++q) {
        int d5 = wv * 4 + q;
        int d = b * 32 + d5;
        if (d >= NW_) continue;
        int a0 = dbase[d5];
        int n = dbase[d5 + 1] - a0;
        float invdn = (n > 0) ? 1.0f / dden[d5] : 0.0f;
        float c0 = 0.f, c1 = 0.f, c2 = 0.f, c3 = 0.f;
        int j = 0;
        for (; j + 32 <= n; j += 32) {
            int2 ee[8];
#pragma unroll
            for (int u = 0; u < 8; ++u) ee[u] = sorted[a0 + j + u * 4 + qg];
            uint2 zz[8];
#pragma unroll
            for (int u = 0; u < 8; ++u) {
                int srcr = ee[u].y & 0xFFFF;
                zz[u] = *(const uint2*)(z16u + (size_t)srcr * 64 + dl * 4);
            }
#pragma unroll
            for (int u = 0; u < 8; ++u) {
                float ex = __int_as_float(ee[u].x);
                __half2 p0 = *(__half2*)&zz[u].x;
                __half2 p1 = *(__half2*)&zz[u].y;
                c0 = fmaf(ex, __low2float(p0), c0);
                c1 = fmaf(ex, __high2float(p0), c1);
                c2 = fmaf(ex, __low2float(p1), c2);
                c3 = fmaf(ex, __high2float(p1), c3);
            }
        }
        for (; j < n; j += 4) {
            int idx = j + qg;
            int2 e = (idx < n) ? sorted[a0 + idx] : make_int2(0, 0);  // ex=0 -> no-op
            float ex = __int_as_float(e.x);
            int srcr = e.y & 0xFFFF;
            uint2 zv = *(const uint2*)(z16u + (size_t)srcr * 64 + dl * 4);
            __half2 p0 = *(__half2*)&zv.x;
            __half2 p1 = *(__half2*)&zv.y;
            c0 = fmaf(ex, __low2float(p0), c0);
            c1 = fmaf(ex, __high2float(p0), c1);
            c2 = fmaf(ex, __low2float(p1), c2);
            c3 = fmaf(ex, __high2float(p1), c3);
        }
        // combine the 4 edge-slots
        c0 += __shfl_xor(c0, 16, 64); c1 += __shfl_xor(c1, 16, 64);
        c2 += __shfl_xor(c2, 16, 64); c3 += __shfl_xor(c3, 16, 64);
        c0 += __shfl_xor(c0, 32, 64); c1 += __shfl_xor(c1, 32, 64);
        c2 += __shfl_xor(c2, 32, 64); c3 += __shfl_xor(c3, 32, 64);
        if (lane < 16) {
            float4 st = make_float4(c0 * invdn, c1 * invdn, c2 * invdn, c3 * invdn);
            *(float4*)(out + (size_t)d * OUT_DIM_ + lane * 4) = st;
        }
    }
}

extern "C" void kernel_launch(void* const* d_in, const int* in_sizes, int n_in,
                              void* d_out, int out_size, void* d_ws, size_t ws_size,
                              hipStream_t stream) {
    const float* h      = (const float*)d_in[0];
    const float* Wfc    = (const float*)d_in[1];
    const float* w_attn = (const float*)d_in[2];
    const float* weight = (const float*)d_in[3];
    const int*   src    = (const int*)d_in[4];
    const int*   dst    = (const int*)d_in[5];
    int E = in_sizes[3];
    float* out = (float*)d_out;

    int slab_e = (E + NSLAB - 1) / NSLAB;  // 3125 for E=1.6M (must be <= 4096)

    // workspace: edata (8B-aligned) | z16 | t | meta
    int2*     edata = (int2*)d_ws;                                  // E
    __half*   z16   = (__half*)(edata + (size_t)E);                 // NS*64
    float*    t     = (float*)(z16 + (size_t)NS_ * OUT_DIM_);       // NS
    unsigned* meta  = (unsigned*)(t + NS_);                         // NSLAB*NB

    fc_kernel<<<(NS_ + 63) / 64, 256, 0, stream>>>(h, Wfc, w_attn, z16, t);

    partition_kernel<<<NSLAB, 1024, 0, stream>>>(weight, src, dst, t, meta, edata, E, slab_e);

    aggregate_kernel<<<NB, 512, 0, stream>>>(meta, edata, z16, out, slab_e);
}

// Round 13
// 101.763 us; speedup vs baseline: 1.2551x; 1.0536x over previous
//
#include <hip/hip_runtime.h>
#include <hip/hip_fp16.h>
#include <math.h>

#define NS_ 50000
#define NW_ 50000
#define IN_DIM_ 128
#define OUT_DIM_ 64

#define NSLAB 512          // partition slabs; slab_e = 3125 for E=1.6M
#define NB 1563            // buckets = ceil(NW/32), bucket = dst >> 5
#define CAPS 1280          // staging capacity (mean 1024, +8 sigma; verified R11/R12)
#define CAPP 2304          // padded sorted capacity (<= CAPS + 32*31 = 2272)

__device__ inline float leaky01(float x) { return x > 0.0f ? x : 0.01f * x; }

// z = h @ W_fc (fp16 out), fused t[row] = sum_c z[row][c] * w_attn[c]
__global__ __launch_bounds__(256) void fc_kernel(const float* __restrict__ h,
                                                 const float* __restrict__ Wfc,
                                                 const float* __restrict__ w_attn,
                                                 __half* __restrict__ z16,
                                                 float* __restrict__ t) {
    __shared__ float hs[64 * IN_DIM_];   // 32 KB
    int tid = threadIdx.x;
    int lane = tid & 63;
    int wv = tid >> 6;

    float Wc[IN_DIM_];
#pragma unroll
    for (int k = 0; k < IN_DIM_; ++k) Wc[k] = Wfc[k * OUT_DIM_ + lane];  // coalesced
    float wa = w_attn[lane];

    int row0 = blockIdx.x * 64;
    int nrows = NS_ - row0; if (nrows > 64) nrows = 64;

    const float4* hg = (const float4*)(h + (size_t)row0 * IN_DIM_);
    float4* hs4 = (float4*)hs;
    int nv = nrows * (IN_DIM_ / 4);
    for (int i = tid; i < nv; i += 256) hs4[i] = hg[i];
    __syncthreads();

    int rend = wv * 16 + 16; if (rend > nrows) rend = nrows;
    for (int r = wv * 16; r < rend; r += 2) {
        bool two = (r + 1 < rend);
        const float4* h0 = (const float4*)(hs + r * IN_DIM_);
        const float4* h1 = (const float4*)(hs + (two ? r + 1 : r) * IN_DIM_);
        float a0 = 0, a1 = 0, a2 = 0, a3 = 0;
        float b0 = 0, b1 = 0, b2 = 0, b3 = 0;
#pragma unroll
        for (int k4 = 0; k4 < IN_DIM_ / 4; ++k4) {
            float4 u = h0[k4];   // wave-uniform LDS broadcast
            float4 v = h1[k4];
            a0 = fmaf(u.x, Wc[4 * k4 + 0], a0);
            a1 = fmaf(u.y, Wc[4 * k4 + 1], a1);
            a2 = fmaf(u.z, Wc[4 * k4 + 2], a2);
            a3 = fmaf(u.w, Wc[4 * k4 + 3], a3);
            b0 = fmaf(v.x, Wc[4 * k4 + 0], b0);
            b1 = fmaf(v.y, Wc[4 * k4 + 1], b1);
            b2 = fmaf(v.z, Wc[4 * k4 + 2], b2);
            b3 = fmaf(v.w, Wc[4 * k4 + 3], b3);
        }
        float za = (a0 + a1) + (a2 + a3);
        float zb = (b0 + b1) + (b2 + b3);
        z16[(size_t)(row0 + r) * OUT_DIM_ + lane] = __float2half(za);
        if (two) z16[(size_t)(row0 + r + 1) * OUT_DIM_ + lane] = __float2half(zb);
        float ta = za * wa, tb = zb * wa;
#pragma unroll
        for (int off = 32; off > 0; off >>= 1) {
            ta += __shfl_down(ta, off, 64);
            tb += __shfl_down(tb, off, 64);
        }
        if (lane == 0) {
            t[row0 + r] = ta;
            if (two) t[row0 + r + 1] = tb;
        }
    }
}

// One 1024-thread block per slab, single pass over edges; two-level wave scan.
// Metadata packed (cnt<<16)|off, written [slab][bucket] (coalesced).
__global__ __launch_bounds__(1024) void partition_kernel(const float* __restrict__ weight,
                                                         const int* __restrict__ src,
                                                         const int* __restrict__ dst,
                                                         const float* __restrict__ t,
                                                         unsigned* __restrict__ meta_sb,
                                                         int2* __restrict__ edata,
                                                         int E, int slab_e) {
    __shared__ int hist[NB];
    __shared__ int cur[NB];
    __shared__ int wsum[16];
    int tid = threadIdx.x;
    int lane = tid & 63;
    int wv = tid >> 6;
    int s = blockIdx.x;
    int e0 = s * slab_e;
    int e1 = e0 + slab_e; if (e1 > E) e1 = E;
    int cnt = e1 - e0;

    for (int i = tid; i < NB; i += 1024) hist[i] = 0;
    __syncthreads();

    // pass over edges: compute + cache (static reg indices; slab_e <= 4096)
    float exr0 = 0, exr1 = 0, exr2 = 0, exr3 = 0;
    int mr0 = 0, mr1 = 0, mr2 = 0, mr3 = 0;
#define PART_LOAD(P, EXR, MR)                                              \
    {                                                                      \
        int i = tid + (P) * 1024;                                          \
        if (i < cnt) {                                                     \
            int e = e0 + i;                                                \
            int sr = src[e];                                               \
            int d = dst[e];                                                \
            float ev = weight[e] * leaky01(t[sr]);                         \
            EXR = __expf(ev);                                              \
            MR = sr | ((d & 31) << 16) | ((d >> 5) << 21);                 \
            atomicAdd(&hist[d >> 5], 1);                                   \
        }                                                                  \
    }
    PART_LOAD(0, exr0, mr0)
    PART_LOAD(1, exr1, mr1)
    PART_LOAD(2, exr2, mr2)
    PART_LOAD(3, exr3, mr3)
#undef PART_LOAD
    __syncthreads();

    // scan over NB=1563: 2 buckets/thread; wave shfl-scan + cross-wave offsets
    int i0 = 2 * tid, i1 = 2 * tid + 1;
    int h0 = (i0 < NB) ? hist[i0] : 0;
    int h1 = (i1 < NB) ? hist[i1] : 0;
    int pairv = h0 + h1;
    int incl = pairv;
#pragma unroll
    for (int off = 1; off < 64; off <<= 1) {
        int u = __shfl_up(incl, off, 64);
        if (lane >= off) incl += u;
    }
    if (lane == 63) wsum[wv] = incl;
    __syncthreads();
    int woff = 0;
    for (int w = 0; w < wv; ++w) woff += wsum[w];
    incl += woff;
    int base = incl - pairv;   // exclusive start of this thread's pair
    if (i0 < NB) {
        cur[i0] = base;
        meta_sb[(size_t)s * NB + i0] = ((unsigned)h0 << 16) | (unsigned)base;
    }
    if (i1 < NB) {
        int b1 = base + h0;
        cur[i1] = b1;
        meta_sb[(size_t)s * NB + i1] = ((unsigned)h1 << 16) | (unsigned)b1;
    }
    __syncthreads();

    // scatter from registers (no re-read)
#define PART_STORE(P, EXR, MR)                                             \
    {                                                                      \
        int i = tid + (P) * 1024;                                          \
        if (i < cnt) {                                                     \
            int b = ((unsigned)MR) >> 21;                                  \
            int pos = atomicAdd(&cur[b], 1);                               \
            edata[e0 + pos] = make_int2(__float_as_int(EXR), MR & 0x1FFFFF); \
        }                                                                  \
    }
    PART_STORE(0, exr0, mr0)
    PART_STORE(1, exr1, mr1)
    PART_STORE(2, exr2, mr2)
    PART_STORE(3, exr3, mr3)
#undef PART_STORE
}

// Tiled transpose of meta [slab][bucket] -> metaT [bucket][slab] (both coalesced)
__global__ __launch_bounds__(256) void meta_transpose_kernel(const unsigned* __restrict__ meta,
                                                             unsigned* __restrict__ metaT) {
    __shared__ unsigned tile[64][65];
    int b0 = blockIdx.x * 64;   // bucket tile (25 tiles)
    int s0 = blockIdx.y * 64;   // slab tile (8 tiles)
    int tx = threadIdx.x & 63, ty = threadIdx.x >> 6;
    for (int r = ty; r < 64; r += 4) {
        int b = b0 + tx;
        tile[r][tx] = (b < NB) ? meta[(size_t)(s0 + r) * NB + b] : 0u;
    }
    __syncthreads();
    for (int r = ty; r < 64; r += 4) {
        int b = b0 + r;
        if (b < NB) metaT[(size_t)b * NSLAB + s0 + tx] = tile[tx][r];
    }
}

// One 512-thread block per bucket (32 dsts), XCD-swizzled block index:
//  pass1: gather bucket segments global->LDS sbuf; per-dst count + den
//  pass2: counting-sort into PADDED sorted[] (each dst padded to 32-multiple
//         with (ex=0) sentinels -> main loop has no remainder, full 8-deep ILP)
//  main:  8 waves x 4 dsts; wide gather (4 edge-slots x 16 dim-slices, uint2)
__global__ __launch_bounds__(512) void aggregate_kernel(const unsigned* __restrict__ metaT,
                                                        const int2* __restrict__ edata,
                                                        const __half* __restrict__ z16,
                                                        float* __restrict__ out,
                                                        int slab_e) {
    __shared__ int2 sbuf[CAPS];           // 10240 B
    __shared__ int2 sorted[CAPP];         // 18432 B (padded)
    __shared__ unsigned short soff[NSLAB];// 1024 B
    __shared__ int arr[NSLAB + 1];        // 2052 B (segment boundaries)
    __shared__ int wsum[8];
    __shared__ float dden[32];
    __shared__ int dcnt[32];              // counts, then padded cursor
    __shared__ int dbase[33];             // padded starts

    // bijective XCD swizzle (m204): consecutive buckets -> same XCD
    int orig = blockIdx.x;
    {
        const int nwg = NB, nx = 8;
        int q = nwg / nx, r = nwg % nx;
        int xcd = orig % nx, idx = orig / nx;
        orig = (xcd < r) ? xcd * (q + 1) + idx : r * (q + 1) + (xcd - r) * q + idx;
    }
    int b = orig;
    int tid = threadIdx.x;
    int lane = tid & 63;
    int wv = tid >> 6;

    int cntv;
    {   // metadata: coalesced 2 KB read (tid == slab id)
        unsigned mv = metaT[(size_t)b * NSLAB + tid];
        soff[tid] = (unsigned short)(mv & 0xFFFFu);
        cntv = (int)(mv >> 16);
    }
    if (tid < 32) { dden[tid] = 0.0f; dcnt[tid] = 0; }
    // zero the padded sorted buffer (sentinels ex=0 are no-ops in the main loop)
    for (int i = tid; i < CAPP; i += 512) sorted[i] = make_int2(0, 0);

    // two-level inclusive scan of cntv -> arr[tid+1]
    int incl = cntv;
#pragma unroll
    for (int off = 1; off < 64; off <<= 1) {
        int u = __shfl_up(incl, off, 64);
        if (lane >= off) incl += u;
    }
    if (lane == 63) wsum[wv] = incl;
    __syncthreads();
    int woff = 0;
    for (int w = 0; w < wv; ++w) woff += wsum[w];
    incl += woff;
    arr[tid + 1] = incl;
    if (tid == 0) arr[0] = 0;
    __syncthreads();

    int total = arr[NSLAB];
    if (total > CAPS) total = CAPS;  // statistically impossible; avoid corruption

    // pass1: copy segments + per-dst count/den. 256 groups x 2 lanes.
    int gid = tid >> 1, l2 = tid & 1;
    for (int s = gid; s < NSLAB; s += 256) {
        int base = arr[s];
        int len = arr[s + 1] - base;
        int so = (int)soff[s];
        for (int j = l2; j < len; j += 2) {
            int p = base + j;
            if (p < CAPS) {
                int2 e = edata[(size_t)s * slab_e + so + j];
                sbuf[p] = e;
                int d5 = (e.y >> 16) & 31;
                atomicAdd(&dcnt[d5], 1);
                atomicAdd(&dden[d5], __int_as_float(e.x));
            }
        }
    }
    __syncthreads();

    // per-dst PADDED exclusive scan (first 32 lanes); dcnt becomes the cursor
    if (tid < 32) {
        int v = dcnt[tid];
        int pv = (v + 31) & ~31;    // pad to multiple of 32
        int iv = pv;
#pragma unroll
        for (int off = 1; off < 32; off <<= 1) {
            int u = __shfl_up(iv, off, 64);
            if (tid >= off) iv += u;
        }
        dbase[tid + 1] = iv;
        dcnt[tid] = iv - pv;   // padded exclusive start = cursor
        if (tid == 0) dbase[0] = 0;
    }
    __syncthreads();

    // pass2: counting-sort payloads into padded sorted[]
    for (int k = tid; k < total; k += 512) {
        int2 e = sbuf[k];
        int d5 = (e.y >> 16) & 31;
        int pos = atomicAdd(&dcnt[d5], 1);
        if (pos < CAPP) sorted[pos] = e;
    }
    __syncthreads();

    // main: 8 waves x 4 dsts; padded wide-gather loop (no remainder)
    int qg = lane >> 4;    // edge slot 0..3
    int dl = lane & 15;    // dim slice: dims dl*4 .. dl*4+3
    const unsigned short* z16u = (const unsigned short*)z16;
    for (int q = 0; q < 4; ++q) {
        int d5 = wv * 4 + q;
        int d = b * 32 + d5;
        if (d >= NW_) continue;
        int a0 = dbase[d5];
        int npad = dbase[d5 + 1] - a0;   // multiple of 32
        float dn = dden[d5];
        float invdn = (dn > 0.0f) ? 1.0f / dn : 0.0f;
        float c0 = 0.f, c1 = 0.f, c2 = 0.f, c3 = 0.f;
        for (int j = 0; j < npad; j += 32) {
            int2 ee[8];
#pragma unroll
            for (int u = 0; u < 8; ++u) ee[u] = sorted[a0 + j + u * 4 + qg];
            uint2 zz[8];
#pragma unroll
            for (int u = 0; u < 8; ++u) {
                int srcr = ee[u].y & 0xFFFF;
                zz[u] = *(const uint2*)(z16u + (size_t)srcr * 64 + dl * 4);
            }
#pragma unroll
            for (int u = 0; u < 8; ++u) {
                float ex = __int_as_float(ee[u].x);
                __half2 p0 = *(__half2*)&zz[u].x;
                __half2 p1 = *(__half2*)&zz[u].y;
                c0 = fmaf(ex, __low2float(p0), c0);
                c1 = fmaf(ex, __high2float(p0), c1);
                c2 = fmaf(ex, __low2float(p1), c2);
                c3 = fmaf(ex, __high2float(p1), c3);
            }
        }
        // combine the 4 edge-slots
        c0 += __shfl_xor(c0, 16, 64); c1 += __shfl_xor(c1, 16, 64);
        c2 += __shfl_xor(c2, 16, 64); c3 += __shfl_xor(c3, 16, 64);
        c0 += __shfl_xor(c0, 32, 64); c1 += __shfl_xor(c1, 32, 64);
        c2 += __shfl_xor(c2, 32, 64); c3 += __shfl_xor(c3, 32, 64);
        if (lane < 16) {
            float4 st = make_float4(c0 * invdn, c1 * invdn, c2 * invdn, c3 * invdn);
            *(float4*)(out + (size_t)d * OUT_DIM_ + lane * 4) = st;
        }
    }
}

extern "C" void kernel_launch(void* const* d_in, const int* in_sizes, int n_in,
                              void* d_out, int out_size, void* d_ws, size_t ws_size,
                              hipStream_t stream) {
    const float* h      = (const float*)d_in[0];
    const float* Wfc    = (const float*)d_in[1];
    const float* w_attn = (const float*)d_in[2];
    const float* weight = (const float*)d_in[3];
    const int*   src    = (const int*)d_in[4];
    const int*   dst    = (const int*)d_in[5];
    int E = in_sizes[3];
    float* out = (float*)d_out;

    int slab_e = (E + NSLAB - 1) / NSLAB;  // 3125 for E=1.6M (must be <= 4096)

    // workspace: edata (8B-aligned) | z16 | t | meta | metaT
    int2*     edata = (int2*)d_ws;                                  // E
    __half*   z16   = (__half*)(edata + (size_t)E);                 // NS*64
    float*    t     = (float*)(z16 + (size_t)NS_ * OUT_DIM_);       // NS
    unsigned* meta  = (unsigned*)(t + NS_);                         // NSLAB*NB
    unsigned* metaT = meta + (size_t)NSLAB * NB;                    // NB*NSLAB

    fc_kernel<<<(NS_ + 63) / 64, 256, 0, stream>>>(h, Wfc, w_attn, z16, t);

    partition_kernel<<<NSLAB, 1024, 0, stream>>>(weight, src, dst, t, meta, edata, E, slab_e);

    dim3 tg((NB + 63) / 64, NSLAB / 64);
    meta_transpose_kernel<<<tg, 256, 0, stream>>>(meta, metaT);

    aggregate_kernel<<<NB, 512, 0, stream>>>(metaT, edata, z16, out, slab_e);
}

// Round 14
// 85.239 us; speedup vs baseline: 1.4984x; 1.1939x over previous
//
#include <hip/hip_runtime.h>
#include <hip/hip_fp16.h>
#include <math.h>

#define NS_ 50000
#define NW_ 50000
#define IN_DIM_ 128
#define OUT_DIM_ 64

#define NSLAB 512          // partition slabs; slab_e = 3125 for E=1.6M
#define NB 1563            // buckets = ceil(NW/32), bucket = dst >> 5
#define CAPS 1280          // staging capacity (mean 1024, +8 sigma; verified R11-R13)
#define CAPP 2304          // padded sorted capacity

typedef _Float16 h16x8 __attribute__((ext_vector_type(8)));
typedef float f32x4 __attribute__((ext_vector_type(4)));

__device__ inline float leaky01(float x) { return x > 0.0f ? x : 0.01f * x; }

// Pack W into fp16 B-frag order (global, L2-resident) and wv128 = W @ wa.
// B-frag (verified R7): for (ni,kstep), lane l holds k=kstep*32+(l>>4)*8+e, c=ni*16+(l&15);
// flat index ((ni*4+kstep)*64 + l)*8 + e.
__global__ __launch_bounds__(256) void prep_kernel(const float* __restrict__ Wfc,
                                                   const float* __restrict__ w_attn,
                                                   __half* __restrict__ W16f,
                                                   float* __restrict__ wv128) {
    int tid = threadIdx.x;
    for (int i = tid; i < IN_DIM_ * OUT_DIM_; i += 256) {
        int k = i >> 6, c = i & 63;
        int ni = c >> 4, c16 = c & 15, kstep = k >> 5, ks = (k & 31) >> 3, el = k & 7;
        W16f[(((ni * 4 + kstep) * 64) + ks * 16 + c16) * 8 + el] = __float2half(Wfc[i]);
    }
    if (tid < IN_DIM_) {
        float s = 0.f;
        for (int c = 0; c < OUT_DIM_; ++c) s += Wfc[tid * OUT_DIM_ + c] * w_attn[c];
        wv128[tid] = s;
    }
}

// MFMA fc: 64 rows/block, 4 waves; wave wv = 16-row tile.
// Staging: coalesced h float4 -> fp16 A-frags (XOR-swizzled LDS) + fused t.
__global__ __launch_bounds__(256) void fc_kernel(const float* __restrict__ h,
                                                 const __half* __restrict__ W16f,
                                                 const float* __restrict__ wv128,
                                                 __half* __restrict__ z16,
                                                 float* __restrict__ t) {
    __shared__ __align__(16) __half Afrag[8192];   // 16 slots x 64 lanes x 8 halfs = 16 KB
    __shared__ float ztile[64][68];                // 17408 B, pad 4
    int tid = threadIdx.x;
    int lane = tid & 63;
    int wv = tid >> 6;
    int row0 = blockIdx.x * 64;

    // ---- staging + fused t ----
    int k0 = (tid & 31) * 4;                 // this thread's k-slice (fixed)
    float4 wvv = *(const float4*)(wv128 + k0);
    int kstep = k0 >> 5, ks = (k0 & 31) >> 3, el = k0 & 7;
#pragma unroll
    for (int iter = 0; iter < 8; ++iter) {
        int r = (tid >> 5) + iter * 8;
        int row = row0 + r;
        float4 hv = (row < NS_) ? *(const float4*)(h + (size_t)row * IN_DIM_ + k0)
                                : make_float4(0.f, 0.f, 0.f, 0.f);
        int slot = ((r >> 4) * 4 + kstep) * 64 + ks * 16 + (r & 15);
        int slw = slot ^ ((slot >> 4) & 7);  // bank swizzle (write side)
        __half2 lo = __floats2half2_rn(hv.x, hv.y);
        __half2 hi = __floats2half2_rn(hv.z, hv.w);
        uint2 pk = make_uint2(*(unsigned*)&lo, *(unsigned*)&hi);
        *(uint2*)(&Afrag[slw * 8 + el]) = pk;
        // t partial over this thread's 4 k; reduce across the 32-thread row group
        float pt = hv.x * wvv.x + hv.y * wvv.y + hv.z * wvv.z + hv.w * wvv.w;
        pt += __shfl_down(pt, 16, 64);
        pt += __shfl_down(pt, 8, 64);
        pt += __shfl_down(pt, 4, 64);
        pt += __shfl_down(pt, 2, 64);
        pt += __shfl_down(pt, 1, 64);
        if ((tid & 31) == 0 && row < NS_) t[row] = pt;
    }
    __syncthreads();

    // ---- MFMA: A-frags from LDS (swizzled read), B-frags from global (L2) ----
    h16x8 af[4];
#pragma unroll
    for (int kst = 0; kst < 4; ++kst) {
        int s = (wv * 4 + kst) * 64 + lane;
        int sr = s ^ ((s >> 4) & 7);
        af[kst] = *(const h16x8*)(&Afrag[sr * 8]);
    }
#pragma unroll
    for (int ni = 0; ni < 4; ++ni) {
        f32x4 acc = {0.f, 0.f, 0.f, 0.f};
#pragma unroll
        for (int kst = 0; kst < 4; ++kst) {
            h16x8 bf = *(const h16x8*)(W16f + ((size_t)(ni * 4 + kst) * 64 + lane) * 8);
            acc = __builtin_amdgcn_mfma_f32_16x16x32_f16(af[kst], bf, acc, 0, 0, 0);
        }
        // C layout (m89/R7): col = lane&15, rows = wv*16 + (lane>>4)*4 + r
        int col = ni * 16 + (lane & 15);
        int rb = wv * 16 + (lane >> 4) * 4;
        ztile[rb + 0][col] = acc[0];
        ztile[rb + 1][col] = acc[1];
        ztile[rb + 2][col] = acc[2];
        ztile[rb + 3][col] = acc[3];
    }
    __syncthreads();

    // ---- z16 writeout: packed half2, coalesced ----
    int nrows = NS_ - row0; if (nrows > 64) nrows = 64;
    for (int j = tid; j < 64 * 32; j += 256) {
        int r = j >> 5, c0 = (j & 31) * 2;
        if (r < nrows) {
            __half2 hp = __floats2half2_rn(ztile[r][c0], ztile[r][c0 + 1]);
            *(__half2*)(z16 + (size_t)(row0 + r) * OUT_DIM_ + c0) = hp;
        }
    }
}

// One 1024-thread block per slab, single pass over edges; two-level wave scan.
// Metadata packed (cnt<<16)|off, written [slab][bucket] (coalesced).
__global__ __launch_bounds__(1024) void partition_kernel(const float* __restrict__ weight,
                                                         const int* __restrict__ src,
                                                         const int* __restrict__ dst,
                                                         const float* __restrict__ t,
                                                         unsigned* __restrict__ meta_sb,
                                                         int2* __restrict__ edata,
                                                         int E, int slab_e) {
    __shared__ int hist[NB];
    __shared__ int cur[NB];
    __shared__ int wsum[16];
    int tid = threadIdx.x;
    int lane = tid & 63;
    int wv = tid >> 6;
    int s = blockIdx.x;
    int e0 = s * slab_e;
    int e1 = e0 + slab_e; if (e1 > E) e1 = E;
    int cnt = e1 - e0;

    for (int i = tid; i < NB; i += 1024) hist[i] = 0;
    __syncthreads();

    float exr0 = 0, exr1 = 0, exr2 = 0, exr3 = 0;
    int mr0 = 0, mr1 = 0, mr2 = 0, mr3 = 0;
#define PART_LOAD(P, EXR, MR)                                              \
    {                                                                      \
        int i = tid + (P) * 1024;                                          \
        if (i < cnt) {                                                     \
            int e = e0 + i;                                                \
            int sr = src[e];                                               \
            int d = dst[e];                                                \
            float ev = weight[e] * leaky01(t[sr]);                         \
            EXR = __expf(ev);                                              \
            MR = sr | ((d & 31) << 16) | ((d >> 5) << 21);                 \
            atomicAdd(&hist[d >> 5], 1);                                   \
        }                                                                  \
    }
    PART_LOAD(0, exr0, mr0)
    PART_LOAD(1, exr1, mr1)
    PART_LOAD(2, exr2, mr2)
    PART_LOAD(3, exr3, mr3)
#undef PART_LOAD
    __syncthreads();

    int i0 = 2 * tid, i1 = 2 * tid + 1;
    int h0 = (i0 < NB) ? hist[i0] : 0;
    int h1 = (i1 < NB) ? hist[i1] : 0;
    int pairv = h0 + h1;
    int incl = pairv;
#pragma unroll
    for (int off = 1; off < 64; off <<= 1) {
        int u = __shfl_up(incl, off, 64);
        if (lane >= off) incl += u;
    }
    if (lane == 63) wsum[wv] = incl;
    __syncthreads();
    int woff = 0;
    for (int w = 0; w < wv; ++w) woff += wsum[w];
    incl += woff;
    int base = incl - pairv;
    if (i0 < NB) {
        cur[i0] = base;
        meta_sb[(size_t)s * NB + i0] = ((unsigned)h0 << 16) | (unsigned)base;
    }
    if (i1 < NB) {
        int b1 = base + h0;
        cur[i1] = b1;
        meta_sb[(size_t)s * NB + i1] = ((unsigned)h1 << 16) | (unsigned)b1;
    }
    __syncthreads();

#define PART_STORE(P, EXR, MR)                                             \
    {                                                                      \
        int i = tid + (P) * 1024;                                          \
        if (i < cnt) {                                                     \
            int b = ((unsigned)MR) >> 21;                                  \
            int pos = atomicAdd(&cur[b], 1);                               \
            edata[e0 + pos] = make_int2(__float_as_int(EXR), MR & 0x1FFFFF); \
        }                                                                  \
    }
    PART_STORE(0, exr0, mr0)
    PART_STORE(1, exr1, mr1)
    PART_STORE(2, exr2, mr2)
    PART_STORE(3, exr3, mr3)
#undef PART_STORE
}

// Tiled transpose of meta [slab][bucket] -> metaT [bucket][slab]
__global__ __launch_bounds__(256) void meta_transpose_kernel(const unsigned* __restrict__ meta,
                                                             unsigned* __restrict__ metaT) {
    __shared__ unsigned tile[64][65];
    int b0 = blockIdx.x * 64;
    int s0 = blockIdx.y * 64;
    int tx = threadIdx.x & 63, ty = threadIdx.x >> 6;
    for (int r = ty; r < 64; r += 4) {
        int b = b0 + tx;
        tile[r][tx] = (b < NB) ? meta[(size_t)(s0 + r) * NB + b] : 0u;
    }
    __syncthreads();
    for (int r = ty; r < 64; r += 4) {
        int b = b0 + r;
        if (b < NB) metaT[(size_t)b * NSLAB + s0 + tx] = tile[tx][r];
    }
}

// One 512-thread block per bucket (32 dsts), XCD-swizzled; padded sorted runs.
__global__ __launch_bounds__(512) void aggregate_kernel(const unsigned* __restrict__ metaT,
                                                        const int2* __restrict__ edata,
                                                        const __half* __restrict__ z16,
                                                        float* __restrict__ out,
                                                        int slab_e) {
    __shared__ int2 sbuf[CAPS];
    __shared__ int2 sorted[CAPP];
    __shared__ unsigned short soff[NSLAB];
    __shared__ int arr[NSLAB + 1];
    __shared__ int wsum[8];
    __shared__ float dden[32];
    __shared__ int dcnt[32];
    __shared__ int dbase[33];

    int orig = blockIdx.x;
    {
        const int nwg = NB, nx = 8;
        int q = nwg / nx, r = nwg % nx;
        int xcd = orig % nx, idx = orig / nx;
        orig = (xcd < r) ? xcd * (q + 1) + idx : r * (q + 1) + (xcd - r) * q + idx;
    }
    int b = orig;
    int tid = threadIdx.x;
    int lane = tid & 63;
    int wv = tid >> 6;

    int cntv;
    {
        unsigned mv = metaT[(size_t)b * NSLAB + tid];
        soff[tid] = (unsigned short)(mv & 0xFFFFu);
        cntv = (int)(mv >> 16);
    }
    if (tid < 32) { dden[tid] = 0.0f; dcnt[tid] = 0; }
    for (int i = tid; i < CAPP; i += 512) sorted[i] = make_int2(0, 0);

    int incl = cntv;
#pragma unroll
    for (int off = 1; off < 64; off <<= 1) {
        int u = __shfl_up(incl, off, 64);
        if (lane >= off) incl += u;
    }
    if (lane == 63) wsum[wv] = incl;
    __syncthreads();
    int woff = 0;
    for (int w = 0; w < wv; ++w) woff += wsum[w];
    incl += woff;
    arr[tid + 1] = incl;
    if (tid == 0) arr[0] = 0;
    __syncthreads();

    int total = arr[NSLAB];
    if (total > CAPS) total = CAPS;

    int gid = tid >> 1, l2 = tid & 1;
    for (int s = gid; s < NSLAB; s += 256) {
        int base = arr[s];
        int len = arr[s + 1] - base;
        int so = (int)soff[s];
        for (int j = l2; j < len; j += 2) {
            int p = base + j;
            if (p < CAPS) {
                int2 e = edata[(size_t)s * slab_e + so + j];
                sbuf[p] = e;
                int d5 = (e.y >> 16) & 31;
                atomicAdd(&dcnt[d5], 1);
                atomicAdd(&dden[d5], __int_as_float(e.x));
            }
        }
    }
    __syncthreads();

    if (tid < 32) {
        int v = dcnt[tid];
        int pv = (v + 31) & ~31;
        int iv = pv;
#pragma unroll
        for (int off = 1; off < 32; off <<= 1) {
            int u = __shfl_up(iv, off, 64);
            if (tid >= off) iv += u;
        }
        dbase[tid + 1] = iv;
        dcnt[tid] = iv - pv;
        if (tid == 0) dbase[0] = 0;
    }
    __syncthreads();

    for (int k = tid; k < total; k += 512) {
        int2 e = sbuf[k];
        int d5 = (e.y >> 16) & 31;
        int pos = atomicAdd(&dcnt[d5], 1);
        if (pos < CAPP) sorted[pos] = e;
    }
    __syncthreads();

    int qg = lane >> 4;
    int dl = lane & 15;
    const unsigned short* z16u = (const unsigned short*)z16;
    for (int q = 0; q < 4; ++q) {
        int d5 = wv * 4 + q;
        int d = b * 32 + d5;
        if (d >= NW_) continue;
        int a0 = dbase[d5];
        int npad = dbase[d5 + 1] - a0;
        float dn = dden[d5];
        float invdn = (dn > 0.0f) ? 1.0f / dn : 0.0f;
        float c0 = 0.f, c1 = 0.f, c2 = 0.f, c3 = 0.f;
        for (int j = 0; j < npad; j += 32) {
            int2 ee[8];
#pragma unroll
            for (int u = 0; u < 8; ++u) ee[u] = sorted[a0 + j + u * 4 + qg];
            uint2 zz[8];
#pragma unroll
            for (int u = 0; u < 8; ++u) {
                int srcr = ee[u].y & 0xFFFF;
                zz[u] = *(const uint2*)(z16u + (size_t)srcr * 64 + dl * 4);
            }
#pragma unroll
            for (int u = 0; u < 8; ++u) {
                float ex = __int_as_float(ee[u].x);
                __half2 p0 = *(__half2*)&zz[u].x;
                __half2 p1 = *(__half2*)&zz[u].y;
                c0 = fmaf(ex, __low2float(p0), c0);
                c1 = fmaf(ex, __high2float(p0), c1);
                c2 = fmaf(ex, __low2float(p1), c2);
                c3 = fmaf(ex, __high2float(p1), c3);
            }
        }
        c0 += __shfl_xor(c0, 16, 64); c1 += __shfl_xor(c1, 16, 64);
        c2 += __shfl_xor(c2, 16, 64); c3 += __shfl_xor(c3, 16, 64);
        c0 += __shfl_xor(c0, 32, 64); c1 += __shfl_xor(c1, 32, 64);
        c2 += __shfl_xor(c2, 32, 64); c3 += __shfl_xor(c3, 32, 64);
        if (lane < 16) {
            float4 st = make_float4(c0 * invdn, c1 * invdn, c2 * invdn, c3 * invdn);
            *(float4*)(out + (size_t)d * OUT_DIM_ + lane * 4) = st;
        }
    }
}

extern "C" void kernel_launch(void* const* d_in, const int* in_sizes, int n_in,
                              void* d_out, int out_size, void* d_ws, size_t ws_size,
                              hipStream_t stream) {
    const float* h      = (const float*)d_in[0];
    const float* Wfc    = (const float*)d_in[1];
    const float* w_attn = (const float*)d_in[2];
    const float* weight = (const float*)d_in[3];
    const int*   src    = (const int*)d_in[4];
    const int*   dst    = (const int*)d_in[5];
    int E = in_sizes[3];
    float* out = (float*)d_out;

    int slab_e = (E + NSLAB - 1) / NSLAB;  // 3125 for E=1.6M (must be <= 4096)

    // workspace: edata | z16 | t | meta | metaT | W16f | wv128
    int2*     edata = (int2*)d_ws;                                  // E
    __half*   z16   = (__half*)(edata + (size_t)E);                 // NS*64
    float*    t     = (float*)(z16 + (size_t)NS_ * OUT_DIM_);       // NS
    unsigned* meta  = (unsigned*)(t + NS_);                         // NSLAB*NB
    unsigned* metaT = meta + (size_t)NSLAB * NB;                    // NB*NSLAB
    __half*   W16f  = (__half*)(metaT + (size_t)NSLAB * NB);        // 8192
    float*    wv128 = (float*)(W16f + 8192);                        // 128

    prep_kernel<<<1, 256, 0, stream>>>(Wfc, w_attn, W16f, wv128);

    fc_kernel<<<(NS_ + 63) / 64, 256, 0, stream>>>(h, W16f, wv128, z16, t);

    partition_kernel<<<NSLAB, 1024, 0, stream>>>(weight, src, dst, t, meta, edata, E, slab_e);

    dim3 tg((NB + 63) / 64, NSLAB / 64);
    meta_transpose_kernel<<<tg, 256, 0, stream>>>(meta, metaT);

    aggregate_kernel<<<NB, 512, 0, stream>>>(metaT, edata, z16, out, slab_e);
}